// Round 17
// baseline (498.107 us; speedup 1.0000x reference)
//
#include <hip/hip_runtime.h>
#include <hip/hip_bf16.h>
#include <math.h>

#define T_TOK 8192
#define NE 1024
#define N_EXP 8
#define DFFN 2048
#define TW 16384        // total width = 8*2048
#define P_TOT 16384     // T_TOK * 2

typedef __attribute__((ext_vector_type(8))) short bf16x8;
typedef __attribute__((ext_vector_type(4))) float f32x4;

#define GLOAD_LDS16(g, l) __builtin_amdgcn_global_load_lds( \
    (const __attribute__((address_space(1))) void*)(g), \
    (__attribute__((address_space(3))) void*)(l), 16, 0, 0)

static __device__ __forceinline__ unsigned short f2bf(float f) {
    __hip_bfloat16 b = __float2bfloat16(f);
    return *(unsigned short*)&b;
}

// fast gelu: x·sigmoid(1.595769x + 0.071355x³)  (tanh-form)
static __device__ __forceinline__ float gelu_fast(float v) {
    float u2 = v * (1.5957691216f + 0.0713548162f * v * v);
    return v / (1.f + __expf(-u2));
}

// ---------------------------------------------------------------------------
// Kernel A: router (+ fused x->bf16 conversion). 8 lanes per token.
// ---------------------------------------------------------------------------
__global__ __launch_bounds__(256) void router_kernel(
    const float* __restrict__ x, const float* __restrict__ wr,
    int* __restrict__ sel_idx, float* __restrict__ sel_wt,
    float* __restrict__ z_part, float* __restrict__ p_part,
    unsigned short* __restrict__ xb)
{
    __shared__ float wrs[N_EXP * NE];   // 32 KB
    __shared__ float zred[32];
    __shared__ float pred[32][8];
    int tid = threadIdx.x;
    for (int i = tid; i < N_EXP * NE / 4; i += 256)
        ((float4*)wrs)[i] = ((const float4*)wr)[i];
    __syncthreads();

    int slot = tid >> 3, oct = tid & 7;
    int t = blockIdx.x * 32 + slot;
    float lg[N_EXP];
#pragma unroll
    for (int e = 0; e < N_EXP; e++) lg[e] = 0.f;

    const float4* x4 = (const float4*)(x + (size_t)t * NE) + oct * 32;
    for (int n4 = 0; n4 < 32; n4++) {
        float4 xv = x4[n4];
        ushort4 o;
        o.x = f2bf(xv.x); o.y = f2bf(xv.y); o.z = f2bf(xv.z); o.w = f2bf(xv.w);
        *(ushort4*)&xb[(size_t)t * NE + oct * 128 + n4 * 4] = o;
#pragma unroll
        for (int e = 0; e < N_EXP; e++) {
            const float* w = &wrs[e * NE + oct * 128 + n4 * 4];
            lg[e] += xv.x * w[0] + xv.y * w[1] + xv.z * w[2] + xv.w * w[3];
        }
    }
#pragma unroll
    for (int d = 1; d < 8; d <<= 1)
#pragma unroll
        for (int e = 0; e < N_EXP; e++) lg[e] += __shfl_xor(lg[e], d);

    float m = lg[0];
#pragma unroll
    for (int e = 1; e < N_EXP; e++) m = fmaxf(m, lg[e]);
    float p[N_EXP], s = 0.f;
#pragma unroll
    for (int e = 0; e < N_EXP; e++) { p[e] = expf(lg[e] - m); s += p[e]; }
    float inv = 1.f / s;
#pragma unroll
    for (int e = 0; e < N_EXP; e++) p[e] *= inv;
    float lse = m + logf(s);

    int e0 = 0;
#pragma unroll
    for (int e = 1; e < N_EXP; e++) if (p[e] > p[e0]) e0 = e;
    int e1 = (e0 == 0) ? 1 : 0;
#pragma unroll
    for (int e = 0; e < N_EXP; e++) if (e != e0 && p[e] > p[e1]) e1 = e;

    if (oct == 0) {
        float wn = 1.f / (p[e0] + p[e1]);
        sel_idx[t * 2 + 0] = e0;
        sel_idx[t * 2 + 1] = e1;
        sel_wt[t * 2 + 0] = p[e0] * wn;
        sel_wt[t * 2 + 1] = p[e1] * wn;
        zred[slot] = lse * lse;
#pragma unroll
        for (int e = 0; e < N_EXP; e++) pred[slot][e] = p[e];
    }
    __syncthreads();
    if (tid == 0) {
        float zs = 0.f;
        for (int i = 0; i < 32; i++) zs += zred[i];
        z_part[blockIdx.x] = zs;
        for (int e = 0; e < N_EXP; e++) {
            float ps = 0.f;
            for (int i = 0; i < 32; i++) ps += pred[i][e];
            p_part[blockIdx.x * N_EXP + e] = ps;
        }
    }
}

// ---------------------------------------------------------------------------
// Kernel B: counts, offsets, cursors, aux losses — parallel reductions
// ---------------------------------------------------------------------------
__global__ __launch_bounds__(256) void finalize_router(
    const int* __restrict__ sel_idx,
    const float* __restrict__ z_part, const float* __restrict__ p_part,
    int* __restrict__ cnt, int* __restrict__ off, int* __restrict__ cursor,
    float* __restrict__ out)
{
    __shared__ int redc[256];
    __shared__ float redf[256];
    __shared__ int cnts[N_EXP];
    __shared__ float psum[N_EXP];
    __shared__ float zsum;
    int tid = threadIdx.x;

    int c[N_EXP];
#pragma unroll
    for (int e = 0; e < N_EXP; e++) c[e] = 0;
    for (int i = tid; i < P_TOT; i += 256) c[sel_idx[i]]++;
#pragma unroll
    for (int e = 0; e < N_EXP; e++) {
        redc[tid] = c[e];
        __syncthreads();
        for (int st = 128; st > 0; st >>= 1) {
            if (tid < st) redc[tid] += redc[tid + st];
            __syncthreads();
        }
        if (tid == 0) cnts[e] = redc[0];
        __syncthreads();
    }

    redf[tid] = z_part[tid];
    __syncthreads();
    for (int st = 128; st > 0; st >>= 1) {
        if (tid < st) redf[tid] += redf[tid + st];
        __syncthreads();
    }
    if (tid == 0) zsum = redf[0];
    __syncthreads();

#pragma unroll
    for (int e = 0; e < N_EXP; e++) {
        redf[tid] = p_part[tid * N_EXP + e];
        __syncthreads();
        for (int st = 128; st > 0; st >>= 1) {
            if (tid < st) redf[tid] += redf[tid + st];
            __syncthreads();
        }
        if (tid == 0) psum[e] = redf[0];
        __syncthreads();
    }

    if (tid == 0) {
        int o = 0;
        for (int e = 0; e < N_EXP; e++) {
            cnt[e] = cnts[e];
            off[e] = o;
            o += cnts[e];
            cursor[e] = 0;
        }
        off[N_EXP] = o;
        float lb = 0.f;
        float* tail = out + (size_t)T_TOK * NE;
        for (int e = 0; e < N_EXP; e++) {
            float fi = (float)cnts[e] / (float)P_TOT;
            float pi = psum[e] / (float)T_TOK;
            lb += fi * pi;
            tail[2 + e] = fi;
        }
        tail[0] = zsum / (float)T_TOK;     // router_z_loss
        tail[1] = 8.f * lb;                // load_balance_loss
    }
}

// ---------------------------------------------------------------------------
// Kernel C: scatter (token,slot) pairs into per-expert lists
// ---------------------------------------------------------------------------
__global__ __launch_bounds__(256) void scatter_kernel(
    const int* __restrict__ sel_idx, const int* __restrict__ off,
    int* __restrict__ cursor, int* __restrict__ token_list)
{
    int i = blockIdx.x * 256 + threadIdx.x;
    if (i < P_TOT) {
        int e = sel_idx[i];
        int pos = atomicAdd(&cursor[e], 1);
        token_list[off[e] + pos] = i;   // token = i>>1, slot = i&1
    }
}

// ---------------------------------------------------------------------------
// Kernel P2: fused transpose+convert for BOTH weight matrices.
// ---------------------------------------------------------------------------
__global__ __launch_bounds__(256) void transpose_both_kernel(
    const float* __restrict__ w1, unsigned short* __restrict__ w1t,
    const float* __restrict__ w2, unsigned short* __restrict__ w2t)
{
    __shared__ float tile[64][65];
    const float* src;
    unsigned short* dst;
    int R, C, rb, cb;
    int bid = blockIdx.x;
    if (bid < 4096) {                 // w1: R=NE, C=TW
        src = w1; dst = w1t; R = NE; C = TW;
        cb = (bid & 255) * 64; rb = (bid >> 8) * 64;
    } else {                          // w2: R=TW, C=NE
        int b2 = bid - 4096;
        src = w2; dst = w2t; R = TW; C = NE;
        cb = (b2 & 15) * 64; rb = (b2 >> 4) * 64;
    }
    int tid = threadIdx.x;
#pragma unroll
    for (int p = 0; p < 4; p++) {
        int idx = p * 256 + tid;
        int r = idx >> 4, c4 = (idx & 15) << 2;
        float4 v = *(const float4*)&src[(size_t)(rb + r) * C + cb + c4];
        tile[r][c4 + 0] = v.x; tile[r][c4 + 1] = v.y;
        tile[r][c4 + 2] = v.z; tile[r][c4 + 3] = v.w;
    }
    __syncthreads();
#pragma unroll
    for (int p = 0; p < 4; p++) {
        int idx = p * 256 + tid;
        int c = idx >> 4, r4 = (idx & 15) << 2;
        ushort4 o;
        o.x = f2bf(tile[r4 + 0][c]); o.y = f2bf(tile[r4 + 1][c]);
        o.z = f2bf(tile[r4 + 2][c]); o.w = f2bf(tile[r4 + 3][c]);
        *(ushort4*)&dst[(size_t)(cb + c) * R + rb + r4] = o;
    }
}

// ---------------------------------------------------------------------------
// GEMM core, round 17 (= round 16 + av/bv declaration fix):
// 256x256 tile, BK=64, 8 waves (2Mx4N), per-wave 128x64 (acc[8][4]).
// 128 KB dbuf LDS. 4 phases per K-tile; each:
//   {ds_read one register subtile || stage one 16KB half-tile} -> barrier ->
//   lgkmcnt(0) -> setprio(1) + 16 MFMA + setprio(0) -> barrier
// Certification: per-wave vmcnt(2) at phase 0 (after issuing own 2 stage
// loads) proves its previous-iter 8 loads landed; barrier extends to all
// waves. Stage->read lead = 1-4 phases; vmcnt never drains mid-loop.
// 8-slot XOR swizzle (BK=64 rows = 8x16B): source slot ksw8=(lane&7)^(lane>>3);
// read slot (kk*4+kq)^(rr&7). av lifetime: loaded ph0, used ph0-1;
// reloaded ph2, used ph2-3. bv[0..3] ph0, bv[4..7] ph1; reused ph2/ph3
// (B fragments are mh-independent).
// ---------------------------------------------------------------------------
#define BAR   __builtin_amdgcn_s_barrier()
#define SB0   __builtin_amdgcn_sched_barrier(0)
#define LGKM0 asm volatile("s_waitcnt lgkmcnt(0)" ::: "memory")
#define VMC(n) asm volatile("s_waitcnt vmcnt(" #n ")" ::: "memory")

#define STG_A(hh, koff, nb) do {                                          \
    GLOAD_LDS16(aS[hh][0] + (koff), Asm + (nb) + (hh)*8192 + wid*1024 + lane*8); \
    GLOAD_LDS16(aS[hh][1] + (koff), Asm + (nb) + (hh)*8192 + wid*1024 + 512 + lane*8); \
} while (0)
#define STG_B(hh, koff, nb) do {                                          \
    GLOAD_LDS16(bS[hh][0] + (koff), Bsm + (nb) + (hh)*8192 + wid*1024 + lane*8); \
    GLOAD_LDS16(bS[hh][1] + (koff), Bsm + (nb) + (hh)*8192 + wid*1024 + 512 + lane*8); \
} while (0)

#define RD_A(mh, cb) do {                                                 \
    _Pragma("unroll")                                                     \
    for (int m4 = 0; m4 < 4; m4++) {                                      \
        int ro = (wm*128 + ((mh)*4 + m4)*16 + rr) * 64;                   \
        av[m4*2 + 0] = *(const bf16x8*)&Asm[(cb) + ro + ks0];             \
        av[m4*2 + 1] = *(const bf16x8*)&Asm[(cb) + ro + ks1];             \
    } } while (0)
#define RD_B(nh, cb) do {                                                 \
    _Pragma("unroll")                                                     \
    for (int n2 = 0; n2 < 2; n2++) {                                      \
        int ro = (wn*64 + ((nh)*2 + n2)*16 + rr) * 64;                    \
        bv[(nh)*4 + n2*2 + 0] = *(const bf16x8*)&Bsm[(cb) + ro + ks0];    \
        bv[(nh)*4 + n2*2 + 1] = *(const bf16x8*)&Bsm[(cb) + ro + ks1];    \
    } } while (0)

#define MFMA_Q(mh, nh) do {                                               \
    __builtin_amdgcn_s_setprio(1);                                        \
    _Pragma("unroll")                                                     \
    for (int m4 = 0; m4 < 4; m4++)                                        \
        _Pragma("unroll")                                                 \
        for (int n2 = 0; n2 < 2; n2++) {                                  \
            acc[(mh)*4+m4][(nh)*2+n2] = __builtin_amdgcn_mfma_f32_16x16x32_bf16( \
                av[m4*2+0], bv[(nh)*4+n2*2+0], acc[(mh)*4+m4][(nh)*2+n2], 0, 0, 0); \
            acc[(mh)*4+m4][(nh)*2+n2] = __builtin_amdgcn_mfma_f32_16x16x32_bf16( \
                av[m4*2+1], bv[(nh)*4+n2*2+1], acc[(mh)*4+m4][(nh)*2+n2], 0, 0, 0); \
        }                                                                 \
    __builtin_amdgcn_s_setprio(0);                                        \
} while (0)

#define GEMM_CORE(NKT)                                                    \
    bf16x8 av[8], bv[8];                                                  \
    STG_A(0, 0, 0); STG_A(1, 0, 0); STG_B(0, 0, 0); STG_B(1, 0, 0);       \
    VMC(0); BAR;                                                          \
    for (int t = 0; t < (NKT); t++) {                                     \
        int cb = (t & 1) << 14;                                           \
        int nb = cb ^ 16384;                                              \
        int koff = (t + 1) * 64;                                          \
        bool pf = (t + 1 < (NKT));                                        \
        /* phase 0 */                                                     \
        if (pf) { STG_A(0, koff, nb); SB0; VMC(2); } else { VMC(0); }     \
        BAR;                                                              \
        RD_A(0, cb); RD_B(0, cb);                                         \
        LGKM0; SB0;                                                       \
        MFMA_Q(0, 0);                                                     \
        SB0; BAR;                                                         \
        /* phase 1 */                                                     \
        RD_B(1, cb);                                                      \
        if (pf) STG_A(1, koff, nb);                                       \
        BAR; LGKM0; SB0;                                                  \
        MFMA_Q(0, 1);                                                     \
        SB0; BAR;                                                         \
        /* phase 2 */                                                     \
        RD_A(1, cb);                                                      \
        if (pf) STG_B(0, koff, nb);                                       \
        BAR; LGKM0; SB0;                                                  \
        MFMA_Q(1, 0);                                                     \
        SB0; BAR;                                                         \
        /* phase 3 */                                                     \
        if (pf) STG_B(1, koff, nb);                                       \
        BAR;                                                              \
        MFMA_Q(1, 1);                                                     \
        SB0; BAR;                                                         \
    }

#define GEMM_SETUP16()                                                    \
    int tid = threadIdx.x;                                                \
    int wid = tid >> 6, lane = tid & 63;                                  \
    int wm = wid >> 2, wn = wid & 3;                                      \
    int rr = lane & 15, kq = lane >> 4;                                   \
    int rs = rr & 7;                                                      \
    int ks0 = (kq ^ rs) * 8;                                              \
    int ks1 = ((4 + kq) ^ rs) * 8;                                        \
    int ksw8 = (lane & 7) ^ (lane >> 3);                                  \
    int lrow = lane >> 3;

// ---------------------------------------------------------------------------
// Kernel D: grouped GEMM1:  h[p,:] = selw[p] * gelu(xb[tok(p),:] @ W1_e)
// grid 512: expert = b&7 (XCD-pinned); slot = b>>3 in [0,64); job j stride 64:
// rowtile = j>>3, col = (j&7)*256  (col-fastest -> A panel L2-shared).
// ---------------------------------------------------------------------------
__global__ __launch_bounds__(512) void gemm1_mfma(
    const __hip_bfloat16* __restrict__ xb, const __hip_bfloat16* __restrict__ w1t,
    const int* __restrict__ token_list, const float* __restrict__ sel_wt,
    const int* __restrict__ cnt, const int* __restrict__ off,
    __hip_bfloat16* __restrict__ hout)
{
    extern __shared__ __align__(16) __hip_bfloat16 smem[];
    __hip_bfloat16* Asm = smem;            // 2 x 16384 elems (64 KB)
    __hip_bfloat16* Bsm = smem + 32768;    // 2 x 16384 elems (64 KB)

    int b = blockIdx.x;
    int e = b & 7;
    int cnt_e = cnt[e], off_e = off[e];
    int nrt = (cnt_e + 255) >> 8;
    int njobs = nrt * 8;

    GEMM_SETUP16()

    for (int j = b >> 3; j < njobs; j += 64) {
        int rowbase = (j >> 3) * 256;
        int colb = (j & 7) * 256;
        int rows_e = cnt_e - rowbase;

        const __hip_bfloat16* aS[2][2];
        const __hip_bfloat16* bS[2][2];
#pragma unroll
        for (int hh = 0; hh < 2; hh++)
#pragma unroll
            for (int jj = 0; jj < 2; jj++) {
                int r = hh * 128 + wid * 16 + jj * 8 + lrow;
                int ent = token_list[off_e + rowbase + ((r < rows_e) ? r : 0)];
                aS[hh][jj] = xb + (size_t)(ent >> 1) * NE + ksw8 * 8;
                bS[hh][jj] = w1t + (size_t)(e * DFFN + colb + r) * NE + ksw8 * 8;
            }

        f32x4 acc[8][4] = {};
        GEMM_CORE(NE / 64)

        int colg = colb + wn * 64;
#pragma unroll
        for (int m = 0; m < 8; m++) {
#pragma unroll
            for (int q4 = 0; q4 < 4; q4++) {
                int r = wm * 128 + m * 16 + kq * 4 + q4;
                if (r < rows_e) {
                    size_t p = (size_t)off_e + rowbase + r;
                    float wgt = sel_wt[token_list[p]];
#pragma unroll
                    for (int n = 0; n < 4; n++) {
                        float g = gelu_fast(acc[m][n][q4]);
                        hout[p * DFFN + colg + n * 16 + rr] = __float2bfloat16(wgt * g);
                    }
                }
            }
        }
        __syncthreads();
    }
}

// ---------------------------------------------------------------------------
// Kernel E: grouped GEMM2:  out[tok(p),:] += h[p,:] @ W2_e  (atomic f32;
// exactly 2 commutative addends per element -> deterministic).
// grid 256: expert = b&7; slot = b>>3 in [0,32); job j stride 32:
// rowtile = j>>2, col = (j&3)*256.
// ---------------------------------------------------------------------------
__global__ __launch_bounds__(512) void gemm2_mfma(
    const __hip_bfloat16* __restrict__ hsrc, const __hip_bfloat16* __restrict__ w2t,
    const int* __restrict__ token_list,
    const int* __restrict__ cnt, const int* __restrict__ off,
    float* __restrict__ out)
{
    extern __shared__ __align__(16) __hip_bfloat16 smem[];
    __hip_bfloat16* Asm = smem;
    __hip_bfloat16* Bsm = smem + 32768;

    int b = blockIdx.x;
    int e = b & 7;
    int cnt_e = cnt[e], off_e = off[e];
    int nrt = (cnt_e + 255) >> 8;
    int njobs = nrt * 4;

    GEMM_SETUP16()

    for (int j = b >> 3; j < njobs; j += 32) {
        int rowbase = (j >> 2) * 256;
        int colb = (j & 3) * 256;
        int rows_e = cnt_e - rowbase;

        const __hip_bfloat16* aS[2][2];
        const __hip_bfloat16* bS[2][2];
#pragma unroll
        for (int hh = 0; hh < 2; hh++)
#pragma unroll
            for (int jj = 0; jj < 2; jj++) {
                int r = hh * 128 + wid * 16 + jj * 8 + lrow;
                int pr = off_e + rowbase + ((r < rows_e) ? r : 0);
                aS[hh][jj] = hsrc + (size_t)pr * DFFN + ksw8 * 8;
                bS[hh][jj] = w2t + (size_t)(colb + r) * TW + e * DFFN + ksw8 * 8;
            }

        f32x4 acc[8][4] = {};
        GEMM_CORE(DFFN / 64)

        int colg = colb + wn * 64;
#pragma unroll
        for (int m = 0; m < 8; m++) {
#pragma unroll
            for (int q4 = 0; q4 < 4; q4++) {
                int r = wm * 128 + m * 16 + kq * 4 + q4;
                if (r < rows_e) {
                    size_t p = (size_t)off_e + rowbase + r;
                    int tok = token_list[p] >> 1;
#pragma unroll
                    for (int n = 0; n < 4; n++)
                        atomicAdd(&out[(size_t)tok * NE + colg + n * 16 + rr],
                                  acc[m][n][q4]);
                }
            }
        }
        __syncthreads();
    }
}

// ---------------------------------------------------------------------------
extern "C" void kernel_launch(void* const* d_in, const int* in_sizes, int n_in,
                              void* d_out, int out_size, void* d_ws, size_t ws_size,
                              hipStream_t stream)
{
    const float* x  = (const float*)d_in[0];
    const float* wr = (const float*)d_in[1];
    const float* w1 = (const float*)d_in[2];
    const float* w2 = (const float*)d_in[3];
    float* out = (float*)d_out;

    // workspace layout (~151.5 MB)
    char* ws = (char*)d_ws;
    size_t o = 0;
    __hip_bfloat16* h   = (__hip_bfloat16*)(ws + o); o += (size_t)P_TOT * DFFN * 2;  // 67.1MB
    __hip_bfloat16* xb  = (__hip_bfloat16*)(ws + o); o += (size_t)T_TOK * NE * 2;    // 16.8MB
    __hip_bfloat16* w1t = (__hip_bfloat16*)(ws + o); o += (size_t)NE * TW * 2;       // 33.6MB  [TW][NE]
    __hip_bfloat16* w2t = (__hip_bfloat16*)(ws + o); o += (size_t)TW * NE * 2;       // 33.6MB  [NE][TW]
    int*   sel_idx    = (int*)(ws + o);   o += P_TOT * 4;
    float* sel_wt     = (float*)(ws + o); o += P_TOT * 4;
    int*   token_list = (int*)(ws + o);   o += P_TOT * 4;
    int*   cnt        = (int*)(ws + o);   o += 64;
    int*   off        = (int*)(ws + o);   o += 64;
    int*   cursor     = (int*)(ws + o);   o += 64;
    float* z_part     = (float*)(ws + o); o += 256 * 4;
    float* p_part     = (float*)(ws + o); o += 256 * N_EXP * 4;

    hipFuncSetAttribute((const void*)gemm1_mfma,
                        hipFuncAttributeMaxDynamicSharedMemorySize, 131072);
    hipFuncSetAttribute((const void*)gemm2_mfma,
                        hipFuncAttributeMaxDynamicSharedMemorySize, 131072);

    hipMemsetAsync(d_out, 0, (size_t)out_size * sizeof(float), stream);

    router_kernel<<<256, 256, 0, stream>>>(x, wr, sel_idx, sel_wt, z_part, p_part,
                                           (unsigned short*)xb);
    transpose_both_kernel<<<8192, 256, 0, stream>>>(
        w1, (unsigned short*)w1t, w2, (unsigned short*)w2t);
    finalize_router<<<1, 256, 0, stream>>>(sel_idx, z_part, p_part, cnt, off, cursor,
                                           out);
    scatter_kernel<<<64, 256, 0, stream>>>(sel_idx, off, cursor, token_list);

    // gemm1: 8 experts x 64 slots = 512 blocks (1 block/CU, 2 rounds)
    gemm1_mfma<<<512, 512, 131072, stream>>>(
        xb, w1t, token_list, sel_wt, cnt, off, h);
    // gemm2: 8 experts x 32 slots = 256 blocks (1 round)
    gemm2_mfma<<<256, 512, 131072, stream>>>(
        h, w2t, token_list, cnt, off, out);
}

// Round 18
// 377.899 us; speedup vs baseline: 1.3181x; 1.3181x over previous
//
#include <hip/hip_runtime.h>
#include <hip/hip_bf16.h>
#include <math.h>

#define T_TOK 8192
#define NE 1024
#define N_EXP 8
#define DFFN 2048
#define TW 16384        // total width = 8*2048
#define P_TOT 16384     // T_TOK * 2

#define BMT 128
#define BNT 128
#define BK9 32

typedef __attribute__((ext_vector_type(8))) short bf16x8;
typedef __attribute__((ext_vector_type(4))) float f32x4;

#define GLOAD_LDS16(g, l) __builtin_amdgcn_global_load_lds( \
    (const __attribute__((address_space(1))) void*)(g), \
    (__attribute__((address_space(3))) void*)(l), 16, 0, 0)

static __device__ __forceinline__ unsigned short f2bf(float f) {
    __hip_bfloat16 b = __float2bfloat16(f);
    return *(unsigned short*)&b;
}

// fast gelu: x·sigmoid(1.595769x + 0.071355x³)  (tanh-form)
static __device__ __forceinline__ float gelu_fast(float v) {
    float u2 = v * (1.5957691216f + 0.0713548162f * v * v);
    return v / (1.f + __expf(-u2));
}

// ---------------------------------------------------------------------------
// Kernel 1: PREP — one launch does: out zero-fill (all blocks), router +
// x->bf16 (blocks 0..255), both weight transposes (blocks 256..8447).
// ---------------------------------------------------------------------------
__global__ __launch_bounds__(256) void prep_kernel(
    const float* __restrict__ x, const float* __restrict__ wr,
    const float* __restrict__ w1, const float* __restrict__ w2,
    int* __restrict__ sel_idx, float* __restrict__ sel_wt,
    float* __restrict__ z_part, float* __restrict__ p_part,
    unsigned short* __restrict__ xb,
    unsigned short* __restrict__ w1t, unsigned short* __restrict__ w2t,
    float* __restrict__ out, int out_n)
{
    __shared__ __align__(16) char sm[N_EXP * NE * 4 + 32 * 4 + 32 * 8 * 4];
    int bid = blockIdx.x;
    int tid = threadIdx.x;

    // cooperative zero of out: block bid covers [bid*1024, bid*1024+1024)
    {
        int base = bid * 1024 + tid * 4;
        if (base + 4 <= out_n) {
            *(float4*)&out[base] = make_float4(0.f, 0.f, 0.f, 0.f);
        } else {
            for (int q = 0; q < 4 && base + q < out_n; q++) out[base + q] = 0.f;
        }
    }

    if (bid < 256) {
        // ---- router path ----
        float* wrs = (float*)sm;                       // 8192 floats
        float* zred = wrs + N_EXP * NE;                // 32
        float (*pred)[8] = (float(*)[8])(zred + 32);   // [32][8]
        for (int i = tid; i < N_EXP * NE / 4; i += 256)
            ((float4*)wrs)[i] = ((const float4*)wr)[i];
        __syncthreads();

        int slot = tid >> 3, oct = tid & 7;
        int t = bid * 32 + slot;
        float lg[N_EXP];
#pragma unroll
        for (int e = 0; e < N_EXP; e++) lg[e] = 0.f;

        const float4* x4 = (const float4*)(x + (size_t)t * NE) + oct * 32;
        for (int n4 = 0; n4 < 32; n4++) {
            float4 xv = x4[n4];
            ushort4 o;
            o.x = f2bf(xv.x); o.y = f2bf(xv.y); o.z = f2bf(xv.z); o.w = f2bf(xv.w);
            *(ushort4*)&xb[(size_t)t * NE + oct * 128 + n4 * 4] = o;
#pragma unroll
            for (int e = 0; e < N_EXP; e++) {
                const float* w = &wrs[e * NE + oct * 128 + n4 * 4];
                lg[e] += xv.x * w[0] + xv.y * w[1] + xv.z * w[2] + xv.w * w[3];
            }
        }
#pragma unroll
        for (int d = 1; d < 8; d <<= 1)
#pragma unroll
            for (int e = 0; e < N_EXP; e++) lg[e] += __shfl_xor(lg[e], d);

        float m = lg[0];
#pragma unroll
        for (int e = 1; e < N_EXP; e++) m = fmaxf(m, lg[e]);
        float p[N_EXP], s = 0.f;
#pragma unroll
        for (int e = 0; e < N_EXP; e++) { p[e] = expf(lg[e] - m); s += p[e]; }
        float inv = 1.f / s;
#pragma unroll
        for (int e = 0; e < N_EXP; e++) p[e] *= inv;
        float lse = m + logf(s);

        int e0 = 0;
#pragma unroll
        for (int e = 1; e < N_EXP; e++) if (p[e] > p[e0]) e0 = e;
        int e1 = (e0 == 0) ? 1 : 0;
#pragma unroll
        for (int e = 0; e < N_EXP; e++) if (e != e0 && p[e] > p[e1]) e1 = e;

        if (oct == 0) {
            float wn = 1.f / (p[e0] + p[e1]);
            sel_idx[t * 2 + 0] = e0;
            sel_idx[t * 2 + 1] = e1;
            sel_wt[t * 2 + 0] = p[e0] * wn;
            sel_wt[t * 2 + 1] = p[e1] * wn;
            zred[slot] = lse * lse;
#pragma unroll
            for (int e = 0; e < N_EXP; e++) pred[slot][e] = p[e];
        }
        __syncthreads();
        if (tid == 0) {
            float zs = 0.f;
            for (int i = 0; i < 32; i++) zs += zred[i];
            z_part[bid] = zs;
            for (int e = 0; e < N_EXP; e++) {
                float ps = 0.f;
                for (int i = 0; i < 32; i++) ps += pred[i][e];
                p_part[bid * N_EXP + e] = ps;
            }
        }
    } else {
        // ---- transpose path ----
        float (*tile)[65] = (float(*)[65])sm;          // 64x65 floats
        const float* src;
        unsigned short* dst;
        int R, C, rb, cb;
        int b2 = bid - 256;
        if (b2 < 4096) {              // w1: [NE][TW] -> w1t [TW][NE]
            src = w1; dst = w1t; R = NE; C = TW;
            cb = (b2 & 255) * 64; rb = (b2 >> 8) * 64;
        } else {                      // w2: [TW][NE] -> w2t [NE][TW]
            int b3 = b2 - 4096;
            src = w2; dst = w2t; R = TW; C = NE;
            cb = (b3 & 15) * 64; rb = (b3 >> 4) * 64;
        }
#pragma unroll
        for (int pph = 0; pph < 4; pph++) {
            int idx = pph * 256 + tid;
            int r = idx >> 4, c4 = (idx & 15) << 2;
            float4 v = *(const float4*)&src[(size_t)(rb + r) * C + cb + c4];
            tile[r][c4 + 0] = v.x; tile[r][c4 + 1] = v.y;
            tile[r][c4 + 2] = v.z; tile[r][c4 + 3] = v.w;
        }
        __syncthreads();
#pragma unroll
        for (int pph = 0; pph < 4; pph++) {
            int idx = pph * 256 + tid;
            int c = idx >> 4, r4 = (idx & 15) << 2;
            ushort4 o;
            o.x = f2bf(tile[r4 + 0][c]); o.y = f2bf(tile[r4 + 1][c]);
            o.z = f2bf(tile[r4 + 2][c]); o.w = f2bf(tile[r4 + 3][c]);
            *(ushort4*)&dst[(size_t)(cb + c) * R + rb + r4] = o;
        }
    }
}

// ---------------------------------------------------------------------------
// Kernel 2: finalize + scatter fused (one block): counts (parallel), offsets,
// aux losses, and token_list build via LDS cursors.
// ---------------------------------------------------------------------------
__global__ __launch_bounds__(256) void finalize_scatter(
    const int* __restrict__ sel_idx,
    const float* __restrict__ z_part, const float* __restrict__ p_part,
    int* __restrict__ cnt, int* __restrict__ off,
    int* __restrict__ token_list,
    float* __restrict__ out)
{
    __shared__ int redc[256];
    __shared__ float redf[256];
    __shared__ int cnts[N_EXP];
    __shared__ int curs[N_EXP];
    __shared__ float psum[N_EXP];
    __shared__ float zsum;
    int tid = threadIdx.x;

    int c[N_EXP];
#pragma unroll
    for (int e = 0; e < N_EXP; e++) c[e] = 0;
    for (int i = tid; i < P_TOT; i += 256) c[sel_idx[i]]++;
#pragma unroll
    for (int e = 0; e < N_EXP; e++) {
        redc[tid] = c[e];
        __syncthreads();
        for (int st = 128; st > 0; st >>= 1) {
            if (tid < st) redc[tid] += redc[tid + st];
            __syncthreads();
        }
        if (tid == 0) cnts[e] = redc[0];
        __syncthreads();
    }

    redf[tid] = z_part[tid];
    __syncthreads();
    for (int st = 128; st > 0; st >>= 1) {
        if (tid < st) redf[tid] += redf[tid + st];
        __syncthreads();
    }
    if (tid == 0) zsum = redf[0];
    __syncthreads();

#pragma unroll
    for (int e = 0; e < N_EXP; e++) {
        redf[tid] = p_part[tid * N_EXP + e];
        __syncthreads();
        for (int st = 128; st > 0; st >>= 1) {
            if (tid < st) redf[tid] += redf[tid + st];
            __syncthreads();
        }
        if (tid == 0) psum[e] = redf[0];
        __syncthreads();
    }

    if (tid == 0) {
        int o = 0;
        for (int e = 0; e < N_EXP; e++) {
            cnt[e] = cnts[e];
            off[e] = o;
            curs[e] = o;
            o += cnts[e];
        }
        off[N_EXP] = o;
        float lb = 0.f;
        float* tail = out + (size_t)T_TOK * NE;
        for (int e = 0; e < N_EXP; e++) {
            float fi = (float)cnts[e] / (float)P_TOT;
            float pi = psum[e] / (float)T_TOK;
            lb += fi * pi;
            tail[2 + e] = fi;
        }
        tail[0] = zsum / (float)T_TOK;     // router_z_loss
        tail[1] = 8.f * lb;                // load_balance_loss
    }
    __syncthreads();

    // scatter: build token_list via LDS cursors (order within expert is
    // arbitrary; all consumers index through token_list consistently)
    for (int i = tid; i < P_TOT; i += 256) {
        int e = sel_idx[i];
        int pos = atomicAdd(&curs[e], 1);
        token_list[pos] = i;   // token = i>>1, slot = i&1
    }
}

// ---------------------------------------------------------------------------
// GEMM core = R15 verbatim (best measured: gemm1 159 / gemm2 158 µs).
// 128x128 tile, BK=32, 4 waves 2x2, acc[4][4], 32 KB LDS dbuf, 4 blocks/CU,
// expert->XCD pinning, zero-conflict XOR swizzle, minimum 2-phase loop:
// STAGE(next) first, reads+MFMA, ONE __syncthreads per K-step.
// ---------------------------------------------------------------------------
#define STG(buf, kb) do {                                                 \
    GLOAD_LDS16(asrc0 + (kb), &As[buf][wid * 1024]);                      \
    GLOAD_LDS16(asrc1 + (kb), &As[buf][wid * 1024 + 512]);                \
    GLOAD_LDS16(bsrc0 + (kb), &Bs[buf][wid * 1024]);                      \
    GLOAD_LDS16(bsrc1 + (kb), &Bs[buf][wid * 1024 + 512]);                \
} while (0)

#define GEMM_LOOP(NKT)                                                    \
    STG(0, 0);                                                            \
    __syncthreads();                                                      \
    for (int t = 0; t < (NKT); t++) {                                     \
        int cur = t & 1;                                                  \
        if (t + 1 < (NKT)) STG(cur ^ 1, (t + 1) * BK9);                   \
        bf16x8 af[4], bfr[4];                                             \
        _Pragma("unroll")                                                 \
        for (int m = 0; m < 4; m++)                                       \
            af[m] = *(const bf16x8*)&As[cur][(wm * 64 + m * 16 + rr) * BK9 + kqa * 8]; \
        _Pragma("unroll")                                                 \
        for (int n = 0; n < 4; n++)                                       \
            bfr[n] = *(const bf16x8*)&Bs[cur][(wn * 64 + n * 16 + rr) * BK9 + kqa * 8]; \
        __builtin_amdgcn_s_setprio(1);                                    \
        _Pragma("unroll")                                                 \
        for (int m = 0; m < 4; m++)                                       \
            _Pragma("unroll")                                             \
            for (int n = 0; n < 4; n++)                                   \
                acc[m][n] = __builtin_amdgcn_mfma_f32_16x16x32_bf16(      \
                    af[m], bfr[n], acc[m][n], 0, 0, 0);                   \
        __builtin_amdgcn_s_setprio(0);                                    \
        __syncthreads();                                                  \
    }

// ---------------------------------------------------------------------------
// Kernel D: grouped GEMM1:  h[p,:] = selw[p] * gelu(xb[tok(p),:] @ W1_e)
// grid 2176: expert = b&7 (XCD-pinned); jobs j = b>>3, step 272;
// rowbase = (j>>4)*128, col = (j&15)*128  (col-fastest -> A panel shared).
// ---------------------------------------------------------------------------
__global__ __launch_bounds__(256, 4) void gemm1_mfma(
    const __hip_bfloat16* __restrict__ xb, const __hip_bfloat16* __restrict__ w1t,
    const int* __restrict__ token_list, const float* __restrict__ sel_wt,
    const int* __restrict__ cnt, const int* __restrict__ off,
    __hip_bfloat16* __restrict__ h)
{
    __shared__ __align__(16) __hip_bfloat16 As[2][BMT * BK9];   // 16 KB
    __shared__ __align__(16) __hip_bfloat16 Bs[2][BNT * BK9];   // 16 KB

    int b = blockIdx.x;
    int e = b & 7;
    int cnt_e = cnt[e];
    int off_e = off[e];
    int njobs = ((cnt_e + BMT - 1) >> 7) * 16;

    int tid = threadIdx.x;
    int wid = tid >> 6, lane = tid & 63;
    int wm = wid >> 1, wn = wid & 1;
    int rr = lane & 15, kq = lane >> 4;
    int kqa = kq ^ ((rr >> 1) & 3);
    int ksw = (lane & 3) ^ ((lane >> 3) & 3);
    int r0 = wid * 32 + (lane >> 2);
    int r1 = r0 + 16;

    for (int j = b >> 3; j < njobs; j += 272) {
        int rowbase = (j >> 4) * BMT;
        int colbase = (j & 15) * BNT;
        int rows_e = cnt_e - rowbase;

        int ent0 = token_list[off_e + rowbase + ((r0 < rows_e) ? r0 : 0)];
        int ent1 = token_list[off_e + rowbase + ((r1 < rows_e) ? r1 : 0)];
        const __hip_bfloat16* asrc0 = xb + (size_t)(ent0 >> 1) * NE + ksw * 8;
        const __hip_bfloat16* asrc1 = xb + (size_t)(ent1 >> 1) * NE + ksw * 8;
        const __hip_bfloat16* bsrc0 = w1t + (size_t)(e * DFFN + colbase + r0) * NE + ksw * 8;
        const __hip_bfloat16* bsrc1 = bsrc0 + (size_t)16 * NE;

        f32x4 acc[4][4] = {};
        GEMM_LOOP(NE / BK9)

        int colg = colbase + wn * 64;
#pragma unroll
        for (int m = 0; m < 4; m++) {
#pragma unroll
            for (int jj = 0; jj < 4; jj++) {
                int r = wm * 64 + m * 16 + kq * 4 + jj;
                if (r < rows_e) {
                    size_t p = (size_t)off_e + rowbase + r;
                    float wgt = sel_wt[token_list[p]];
#pragma unroll
                    for (int n = 0; n < 4; n++) {
                        float g = gelu_fast(acc[m][n][jj]);
                        h[p * DFFN + colg + n * 16 + rr] = __float2bfloat16(wgt * g);
                    }
                }
            }
        }
        __syncthreads();   // protect LDS reuse across jobs
    }
}

// ---------------------------------------------------------------------------
// Kernel E: grouped GEMM2:  out[tok(p),:] += h[p,:] @ W2_e  (atomic f32;
// exactly 2 commutative addends per element -> deterministic).
// grid 1088: expert = b&7 (XCD-pinned); jobs j = b>>3, step 136;
// rowbase = (j>>3)*128, col = (j&7)*128.
// ---------------------------------------------------------------------------
__global__ __launch_bounds__(256, 4) void gemm2_mfma(
    const __hip_bfloat16* __restrict__ h, const __hip_bfloat16* __restrict__ w2t,
    const int* __restrict__ token_list,
    const int* __restrict__ cnt, const int* __restrict__ off,
    float* __restrict__ out)
{
    __shared__ __align__(16) __hip_bfloat16 As[2][BMT * BK9];
    __shared__ __align__(16) __hip_bfloat16 Bs[2][BNT * BK9];

    int b = blockIdx.x;
    int e = b & 7;
    int cnt_e = cnt[e];
    int off_e = off[e];
    int njobs = ((cnt_e + BMT - 1) >> 7) * 8;

    int tid = threadIdx.x;
    int wid = tid >> 6, lane = tid & 63;
    int wm = wid >> 1, wn = wid & 1;
    int rr = lane & 15, kq = lane >> 4;
    int kqa = kq ^ ((rr >> 1) & 3);
    int ksw = (lane & 3) ^ ((lane >> 3) & 3);
    int r0 = wid * 32 + (lane >> 2);
    int r1 = r0 + 16;

    for (int j = b >> 3; j < njobs; j += 136) {
        int rowbase = (j >> 3) * BMT;
        int colbase = (j & 7) * BNT;
        int rows_e = cnt_e - rowbase;

        int pr0 = off_e + rowbase + ((r0 < rows_e) ? r0 : 0);
        int pr1 = off_e + rowbase + ((r1 < rows_e) ? r1 : 0);
        const __hip_bfloat16* asrc0 = h + (size_t)pr0 * DFFN + ksw * 8;
        const __hip_bfloat16* asrc1 = h + (size_t)pr1 * DFFN + ksw * 8;
        const __hip_bfloat16* bsrc0 = w2t + (size_t)(colbase + r0) * TW + e * DFFN + ksw * 8;
        const __hip_bfloat16* bsrc1 = bsrc0 + (size_t)16 * TW;

        f32x4 acc[4][4] = {};
        GEMM_LOOP(DFFN / BK9)

        int colg = colbase + wn * 64;
#pragma unroll
        for (int m = 0; m < 4; m++) {
#pragma unroll
            for (int jj = 0; jj < 4; jj++) {
                int r = wm * 64 + m * 16 + kq * 4 + jj;
                if (r < rows_e) {
                    size_t p = (size_t)off_e + rowbase + r;
                    int tok = token_list[p] >> 1;
#pragma unroll
                    for (int n = 0; n < 4; n++)
                        atomicAdd(&out[(size_t)tok * NE + colg + n * 16 + rr],
                                  acc[m][n][jj]);
                }
            }
        }
        __syncthreads();
    }
}

// ---------------------------------------------------------------------------
extern "C" void kernel_launch(void* const* d_in, const int* in_sizes, int n_in,
                              void* d_out, int out_size, void* d_ws, size_t ws_size,
                              hipStream_t stream)
{
    const float* x  = (const float*)d_in[0];
    const float* wr = (const float*)d_in[1];
    const float* w1 = (const float*)d_in[2];
    const float* w2 = (const float*)d_in[3];
    float* out = (float*)d_out;

    // workspace layout (~151.5 MB)
    char* ws = (char*)d_ws;
    size_t o = 0;
    __hip_bfloat16* h   = (__hip_bfloat16*)(ws + o); o += (size_t)P_TOT * DFFN * 2;  // 67.1MB
    __hip_bfloat16* xb  = (__hip_bfloat16*)(ws + o); o += (size_t)T_TOK * NE * 2;    // 16.8MB
    __hip_bfloat16* w1t = (__hip_bfloat16*)(ws + o); o += (size_t)NE * TW * 2;       // 33.6MB  [TW][NE]
    __hip_bfloat16* w2t = (__hip_bfloat16*)(ws + o); o += (size_t)TW * NE * 2;       // 33.6MB  [NE][TW]
    int*   sel_idx    = (int*)(ws + o);   o += P_TOT * 4;
    float* sel_wt     = (float*)(ws + o); o += P_TOT * 4;
    int*   token_list = (int*)(ws + o);   o += P_TOT * 4;
    int*   cnt        = (int*)(ws + o);   o += 64;
    int*   off        = (int*)(ws + o);   o += 64;
    float* z_part     = (float*)(ws + o); o += 256 * 4;
    float* p_part     = (float*)(ws + o); o += 256 * N_EXP * 4;

    // prep: 256 router blocks + 8192 transpose blocks (+ cooperative zero)
    prep_kernel<<<8448, 256, 0, stream>>>(
        x, wr, w1, w2, sel_idx, sel_wt, z_part, p_part,
        (unsigned short*)xb, (unsigned short*)w1t, (unsigned short*)w2t,
        out, out_size);

    finalize_scatter<<<1, 256, 0, stream>>>(sel_idx, z_part, p_part,
                                            cnt, off, token_list, out);

    // gemm1: 8 experts (==XCDs) x 272 job slots = 2176 blocks
    gemm1_mfma<<<2176, 256, 0, stream>>>(
        xb, w1t, token_list, sel_wt, cnt, off, h);
    // gemm2: 8 experts x 136 job slots = 1088 blocks
    gemm2_mfma<<<1088, 256, 0, stream>>>(
        h, w2t, token_list, cnt, off, out);
}